// Round 6
// baseline (437.819 us; speedup 1.0000x reference)
//
#include <hip/hip_runtime.h>

// Problem constants (from reference)
constexpr int NN = 50000;     // nodes
constexpr int NE = 400000;    // edges
constexpr int NV = 3;         // views
constexpr int DF = 128;       // per-view width
constexpr int F  = 384;       // total feature width (NV*DF)
constexpr int TR = 16;        // node rows per block tile (50000 = 16*3125 exactly)
constexpr int NB = (NN + 255) / 256;  // 196 scan blocks

static_assert(NN % TR == 0, "node tiling must be exact");

// ---------------- CSR build (by destination) ----------------

__global__ void k_count(const int* __restrict__ dst, int* __restrict__ deg) {
  int i = blockIdx.x * blockDim.x + threadIdx.x;
  int stride = gridDim.x * blockDim.x;
  for (int e = i; e < NE; e += stride) atomicAdd(&deg[dst[e]], 1);
}

__global__ void k_blocksum(const int* __restrict__ deg, int* __restrict__ bsum) {
  __shared__ int s[4];
  int i = blockIdx.x * 256 + threadIdx.x;
  int v = (i < NN) ? deg[i] : 0;
  for (int o = 32; o > 0; o >>= 1) v += __shfl_down(v, o);  // wave64 reduce
  if ((threadIdx.x & 63) == 0) s[threadIdx.x >> 6] = v;
  __syncthreads();
  if (threadIdx.x == 0) bsum[blockIdx.x] = s[0] + s[1] + s[2] + s[3];
}

__global__ void k_scanb(int* __restrict__ bsum, int nb, int* __restrict__ offs_n) {
  if (threadIdx.x == 0 && blockIdx.x == 0) {
    int run = 0;
    for (int i = 0; i < nb; ++i) { int v = bsum[i]; bsum[i] = run; run += v; }
    *offs_n = run;  // offs[NN] = NE
  }
}

__global__ void k_offsets(const int* __restrict__ deg, const int* __restrict__ bsum,
                          int* __restrict__ offs) {
  __shared__ int s[256];
  int t = threadIdx.x;
  int i = blockIdx.x * 256 + t;
  int v = (i < NN) ? deg[i] : 0;
  s[t] = v;
  __syncthreads();
  for (int o = 1; o < 256; o <<= 1) {     // Hillis-Steele inclusive scan
    int add = (t >= o) ? s[t - o] : 0;
    __syncthreads();
    s[t] += add;
    __syncthreads();
  }
  if (i < NN) offs[i] = bsum[blockIdx.x] + s[t] - v;  // exclusive
}

__global__ void k_scatter(const int* __restrict__ src, const int* __restrict__ dst,
                          const int* __restrict__ offs, int* __restrict__ cnt,
                          int* __restrict__ csr) {
  int i = blockIdx.x * blockDim.x + threadIdx.x;
  int stride = gridDim.x * blockDim.x;
  for (int e = i; e < NE; e += stride) {
    int d = dst[e];
    int pos = offs[d] + atomicAdd(&cnt[d], 1);
    csr[pos] = src[e];
  }
}

// ---------------- fp32 -> bf16 (RNE) streaming conversion ----------------

__device__ __forceinline__ ushort f2bf(float f) {
  unsigned u = __float_as_uint(f);
  u = (u + 0x7fffu + ((u >> 16) & 1u)) >> 16;   // round-nearest-even
  return (ushort)u;
}

__global__ void k_tobf16(const float* __restrict__ in, ushort* __restrict__ outb, int n4) {
  int i = blockIdx.x * blockDim.x + threadIdx.x;
  int stride = gridDim.x * blockDim.x;
  const float4* in4 = (const float4*)in;
  for (int k = i; k < n4; k += stride) {
    float4 x = in4[k];
    ushort4 u;
    u.x = f2bf(x.x); u.y = f2bf(x.y); u.z = f2bf(x.z); u.w = f2bf(x.w);
    *(ushort4*)(outb + (size_t)k * 4) = u;
  }
}

// ---------------- Fused aggregate + GEMM(+bias+ReLU), all 3 views ----------------
// bf16 features. Per edge: ONE row base address; lane loads 3 dwords (2x bf16
// each) at immediate offsets +0/+256/+512 B -> 12 loads in flight per 4-edge
// unroll off just 4 address pairs; csr/readlane/addr logistics amortized 3x.

__device__ __forceinline__ float4 relu4(float4 a) {
  a.x = a.x > 0.f ? a.x : 0.f;
  a.y = a.y > 0.f ? a.y : 0.f;
  a.z = a.z > 0.f ? a.z : 0.f;
  a.w = a.w > 0.f ? a.w : 0.f;
  return a;
}

template <bool OUT_BF16>
__global__ __launch_bounds__(256, 4)
void k_layer(const ushort* __restrict__ feat,      // bf16 features [NN][F]
             const int* __restrict__ offs, const int* __restrict__ csr,
             const float* __restrict__ Wall, const float* __restrict__ ball,
             int wstride, int bstride, void* __restrict__ outp) {
  __shared__ float sT[TR][F];      // 24 KB aggregated tile (fp32, all views)
  const int t = threadIdx.x;
  const int wave = t >> 6, lane = t & 63;
  const int row0 = blockIdx.x * TR;
  const int lane2 = lane * 2;      // element offset within view 0

  // Phase A: one wave per node-row, 4 rows per wave.
#pragma unroll
  for (int rr = 0; rr < TR / 4; ++rr) {
    const int r = wave * (TR / 4) + rr;
    const int node = row0 + r;
    float a0x = 0.f, a0y = 0.f, a1x = 0.f, a1y = 0.f, a2x = 0.f, a2y = 0.f;
    int e0 = offs[node], e1 = offs[node + 1];
    int e = e0;
    while (e < e1) {                    // wave-uniform loop
      int n = e1 - e; if (n > 64) n = 64;
      int ce = e + lane; if (ce > e1 - 1) ce = e1 - 1;   // clamped coalesced index load
      int idx = csr[ce];
      int j = 0;
      for (; j + 4 <= n; j += 4) {      // 4 edges x 3 views = 12 dword loads in flight
        int s0 = __builtin_amdgcn_readlane(idx, j);
        int s1 = __builtin_amdgcn_readlane(idx, j + 1);
        int s2 = __builtin_amdgcn_readlane(idx, j + 2);
        int s3 = __builtin_amdgcn_readlane(idx, j + 3);
        const ushort* p0 = feat + (size_t)s0 * F + lane2;
        const ushort* p1 = feat + (size_t)s1 * F + lane2;
        const ushort* p2 = feat + (size_t)s2 * F + lane2;
        const ushort* p3 = feat + (size_t)s3 * F + lane2;
        unsigned u00 = *(const unsigned*)(p0);
        unsigned u01 = *(const unsigned*)(p0 + DF);
        unsigned u02 = *(const unsigned*)(p0 + 2 * DF);
        unsigned u10 = *(const unsigned*)(p1);
        unsigned u11 = *(const unsigned*)(p1 + DF);
        unsigned u12 = *(const unsigned*)(p1 + 2 * DF);
        unsigned u20 = *(const unsigned*)(p2);
        unsigned u21 = *(const unsigned*)(p2 + DF);
        unsigned u22 = *(const unsigned*)(p2 + 2 * DF);
        unsigned u30 = *(const unsigned*)(p3);
        unsigned u31 = *(const unsigned*)(p3 + DF);
        unsigned u32 = *(const unsigned*)(p3 + 2 * DF);
        a0x += __uint_as_float(u00 << 16); a0y += __uint_as_float(u00 & 0xffff0000u);
        a1x += __uint_as_float(u01 << 16); a1y += __uint_as_float(u01 & 0xffff0000u);
        a2x += __uint_as_float(u02 << 16); a2y += __uint_as_float(u02 & 0xffff0000u);
        a0x += __uint_as_float(u10 << 16); a0y += __uint_as_float(u10 & 0xffff0000u);
        a1x += __uint_as_float(u11 << 16); a1y += __uint_as_float(u11 & 0xffff0000u);
        a2x += __uint_as_float(u12 << 16); a2y += __uint_as_float(u12 & 0xffff0000u);
        a0x += __uint_as_float(u20 << 16); a0y += __uint_as_float(u20 & 0xffff0000u);
        a1x += __uint_as_float(u21 << 16); a1y += __uint_as_float(u21 & 0xffff0000u);
        a2x += __uint_as_float(u22 << 16); a2y += __uint_as_float(u22 & 0xffff0000u);
        a0x += __uint_as_float(u30 << 16); a0y += __uint_as_float(u30 & 0xffff0000u);
        a1x += __uint_as_float(u31 << 16); a1y += __uint_as_float(u31 & 0xffff0000u);
        a2x += __uint_as_float(u32 << 16); a2y += __uint_as_float(u32 & 0xffff0000u);
      }
      for (; j < n; ++j) {
        int s0 = __builtin_amdgcn_readlane(idx, j);
        const ushort* p0 = feat + (size_t)s0 * F + lane2;
        unsigned u00 = *(const unsigned*)(p0);
        unsigned u01 = *(const unsigned*)(p0 + DF);
        unsigned u02 = *(const unsigned*)(p0 + 2 * DF);
        a0x += __uint_as_float(u00 << 16); a0y += __uint_as_float(u00 & 0xffff0000u);
        a1x += __uint_as_float(u01 << 16); a1y += __uint_as_float(u01 & 0xffff0000u);
        a2x += __uint_as_float(u02 << 16); a2y += __uint_as_float(u02 & 0xffff0000u);
      }
      e += n;
    }
    *(float2*)&sT[r][lane2]          = make_float2(a0x, a0y);
    *(float2*)&sT[r][DF + lane2]     = make_float2(a1x, a1y);
    *(float2*)&sT[r][2 * DF + lane2] = make_float2(a2x, a2y);
  }
  __syncthreads();

  // Phase B: per-view GEMM. Thread tile = 2 rows x 4 cols; W from global (L1/L2).
  const int cg = t & 31, rg = t >> 5;
  const int c = cg * 4;
#pragma unroll
  for (int v = 0; v < NV; ++v) {
    const float* __restrict__ W = Wall + (size_t)v * wstride;
    const float* __restrict__ bias = ball + (size_t)v * bstride;
    const float4* __restrict__ W4 = (const float4*)W;
    const float4 b4 = *(const float4*)(bias + c);
    float4 a0 = b4, a1 = b4;
#pragma unroll 8
    for (int d = 0; d < DF; ++d) {
      float4 w = W4[d * (DF / 4) + cg];
      float x0 = sT[rg * 2 + 0][v * DF + d];
      float x1 = sT[rg * 2 + 1][v * DF + d];
      a0.x = fmaf(x0, w.x, a0.x); a0.y = fmaf(x0, w.y, a0.y);
      a0.z = fmaf(x0, w.z, a0.z); a0.w = fmaf(x0, w.w, a0.w);
      a1.x = fmaf(x1, w.x, a1.x); a1.y = fmaf(x1, w.y, a1.y);
      a1.z = fmaf(x1, w.z, a1.z); a1.w = fmaf(x1, w.w, a1.w);
    }
    const int nodeb = row0 + rg * 2;
    if (OUT_BF16) {
      ushort* ob = (ushort*)outp;
      float4 r0 = relu4(a0), r1 = relu4(a1);
      ushort4 u0, u1;
      u0.x = f2bf(r0.x); u0.y = f2bf(r0.y); u0.z = f2bf(r0.z); u0.w = f2bf(r0.w);
      u1.x = f2bf(r1.x); u1.y = f2bf(r1.y); u1.z = f2bf(r1.z); u1.w = f2bf(r1.w);
      *(ushort4*)(ob + (size_t)(nodeb + 0) * F + v * DF + c) = u0;
      *(ushort4*)(ob + (size_t)(nodeb + 1) * F + v * DF + c) = u1;
    } else {
      float* of = (float*)outp;
      *(float4*)(of + (size_t)(nodeb + 0) * F + v * DF + c) = relu4(a0);
      *(float4*)(of + (size_t)(nodeb + 1) * F + v * DF + c) = relu4(a1);
    }
  }
}

// ---------------- launch ----------------

static inline size_t align_up(size_t x, size_t a) { return (x + a - 1) & ~(a - 1); }

extern "C" void kernel_launch(void* const* d_in, const int* in_sizes, int n_in,
                              void* d_out, int out_size, void* d_ws, size_t ws_size,
                              hipStream_t stream) {
  const float* h   = (const float*)d_in[0];
  const int*   src = (const int*)d_in[1];
  const int*   dst = (const int*)d_in[2];
  const float* W1  = (const float*)d_in[3];
  const float* b1  = (const float*)d_in[4];
  const float* W2  = (const float*)d_in[5];
  const float* b2  = (const float*)d_in[6];
  float* out = (float*)d_out;

  // Workspace layout
  char* ws = (char*)d_ws;
  size_t o = 0;
  int* deg  = (int*)(ws + o); o = align_up(o + (size_t)NN * 4, 1024);        // also reused as scatter cursor
  int* offs = (int*)(ws + o); o = align_up(o + (size_t)(NN + 1) * 4, 1024);
  int* bsum = (int*)(ws + o); o = align_up(o + 1024, 1024);
  int* csr  = (int*)(ws + o); o = align_up(o + (size_t)NE * 4, 1024);
  ushort* hb   = (ushort*)(ws + o); o = align_up(o + (size_t)NN * F * 2, 1024);  // bf16 h
  ushort* ybuf = (ushort*)(ws + o); o = align_up(o + (size_t)NN * F * 2, 1024);  // bf16 y
  (void)ws_size; (void)n_in; (void)in_sizes; (void)out_size;

  // CSR build + bf16 conversion
  hipMemsetAsync(deg, 0, (size_t)NN * 4, stream);
  k_count<<<1024, 256, 0, stream>>>(dst, deg);
  k_blocksum<<<NB, 256, 0, stream>>>(deg, bsum);
  k_scanb<<<1, 64, 0, stream>>>(bsum, NB, offs + NN);
  k_offsets<<<NB, 256, 0, stream>>>(deg, bsum, offs);
  hipMemsetAsync(deg, 0, (size_t)NN * 4, stream);  // reuse as per-node cursor
  k_scatter<<<1024, 256, 0, stream>>>(src, dst, offs, deg, csr);
  k_tobf16<<<2048, 256, 0, stream>>>(h, hb, NN * F / 4);

  // Two fused layers: layer1 per-view W1/b1 (bf16 out), layer2 shared W2/b2 (fp32 out)
  const int grid = NN / TR;  // 3125
  k_layer<true ><<<grid, 256, 0, stream>>>(hb,   offs, csr, W1, b1, DF * DF, DF, ybuf);
  k_layer<false><<<grid, 256, 0, stream>>>(ybuf, offs, csr, W2, b2, 0,       0,  out);
}

// Round 7
// 384.297 us; speedup vs baseline: 1.1393x; 1.1393x over previous
//
#include <hip/hip_runtime.h>

// Problem constants (from reference)
constexpr int NN = 50000;     // nodes
constexpr int NE = 400000;    // edges
constexpr int NV = 3;         // views
constexpr int DF = 128;       // per-view width
constexpr int F  = 384;       // total feature width (NV*DF)
constexpr int TR = 32;        // node rows per block tile
constexpr int NB = (NN + 255) / 256;  // 196 scan blocks

// ---------------- CSR build (by destination) ----------------

__global__ void k_count(const int* __restrict__ dst, int* __restrict__ deg) {
  int i = blockIdx.x * blockDim.x + threadIdx.x;
  int stride = gridDim.x * blockDim.x;
  for (int e = i; e < NE; e += stride) atomicAdd(&deg[dst[e]], 1);
}

__global__ void k_blocksum(const int* __restrict__ deg, int* __restrict__ bsum) {
  __shared__ int s[4];
  int i = blockIdx.x * 256 + threadIdx.x;
  int v = (i < NN) ? deg[i] : 0;
  for (int o = 32; o > 0; o >>= 1) v += __shfl_down(v, o);  // wave64 reduce
  if ((threadIdx.x & 63) == 0) s[threadIdx.x >> 6] = v;
  __syncthreads();
  if (threadIdx.x == 0) bsum[blockIdx.x] = s[0] + s[1] + s[2] + s[3];
}

__global__ void k_scanb(int* __restrict__ bsum, int nb, int* __restrict__ offs_n) {
  if (threadIdx.x == 0 && blockIdx.x == 0) {
    int run = 0;
    for (int i = 0; i < nb; ++i) { int v = bsum[i]; bsum[i] = run; run += v; }
    *offs_n = run;  // offs[NN] = NE
  }
}

__global__ void k_offsets(const int* __restrict__ deg, const int* __restrict__ bsum,
                          int* __restrict__ offs, int* __restrict__ cur) {
  __shared__ int s[256];
  int t = threadIdx.x;
  int i = blockIdx.x * 256 + t;
  int v = (i < NN) ? deg[i] : 0;
  s[t] = v;
  __syncthreads();
  for (int o = 1; o < 256; o <<= 1) {     // Hillis-Steele inclusive scan
    int add = (t >= o) ? s[t - o] : 0;
    __syncthreads();
    s[t] += add;
    __syncthreads();
  }
  if (i < NN) {
    offs[i] = bsum[blockIdx.x] + s[t] - v;  // exclusive
    cur[i] = 0;                              // zero scatter cursor (saves a memset dispatch)
  }
}

__global__ void k_scatter(const int* __restrict__ src, const int* __restrict__ dst,
                          const int* __restrict__ offs, int* __restrict__ cnt,
                          int* __restrict__ csr) {
  int i = blockIdx.x * blockDim.x + threadIdx.x;
  int stride = gridDim.x * blockDim.x;
  for (int e = i; e < NE; e += stride) {
    int d = dst[e];
    int pos = offs[d] + atomicAdd(&cnt[d], 1);
    csr[pos] = src[e];
  }
}

// ---------------- fp32 -> bf16 (RNE) streaming conversion ----------------

__device__ __forceinline__ ushort f2bf(float f) {
  unsigned u = __float_as_uint(f);
  u = (u + 0x7fffu + ((u >> 16) & 1u)) >> 16;   // round-nearest-even
  return (ushort)u;
}

__global__ void k_tobf16(const float* __restrict__ in, ushort* __restrict__ outb, int n4) {
  int i = blockIdx.x * blockDim.x + threadIdx.x;
  int stride = gridDim.x * blockDim.x;
  const float4* in4 = (const float4*)in;
  for (int k = i; k < n4; k += stride) {
    float4 x = in4[k];
    ushort4 u;
    u.x = f2bf(x.x); u.y = f2bf(x.y); u.z = f2bf(x.z); u.w = f2bf(x.w);
    *(ushort4*)(outb + (size_t)k * 4) = u;
  }
}

// ---------------- Fused aggregate + GEMM(+bias+ReLU) layer ----------------
// Features stored bf16: per edge, lane loads one uint (2x bf16 = 4B); unpack is
// pure bit-ops (bf16->f32 == shift). Accumulate fp32 in LDS; GEMM fp32 VALU.
// __launch_bounds__(256,8): VGPR=32, LDS=16KB -> 8 blocks/CU = 32 waves/CU (100%).

__device__ __forceinline__ float4 relu4(float4 a) {
  a.x = a.x > 0.f ? a.x : 0.f;
  a.y = a.y > 0.f ? a.y : 0.f;
  a.z = a.z > 0.f ? a.z : 0.f;
  a.w = a.w > 0.f ? a.w : 0.f;
  return a;
}

template <bool OUT_BF16>
__global__ __launch_bounds__(256, 8)
void k_layer(const ushort* __restrict__ feat,      // bf16 features [NN][F]
             const int* __restrict__ offs, const int* __restrict__ csr,
             const float* __restrict__ Wall, const float* __restrict__ ball,
             int wstride, int bstride, void* __restrict__ outp) {
  __shared__ float sT[TR][DF];     // 16 KB: aggregated tile (fp32)
  const int t = threadIdx.x;
  const int v = blockIdx.y;
  const float* __restrict__ W = Wall + (size_t)v * wstride;
  const float* __restrict__ bias = ball + (size_t)v * bstride;

  const int wave = t >> 6, lane = t & 63;
  const int row0 = blockIdx.x * TR;
  const int vcol = v * DF + lane * 2;   // element offset within row

#pragma unroll
  for (int rr = 0; rr < TR / 4; ++rr) {
    int r = rr * 4 + wave;
    int node = row0 + r;
    float ax = 0.f, ay = 0.f;
    if (node < NN) {
      int e0 = offs[node], e1 = offs[node + 1];
      int e = e0;
      while (e < e1) {                    // wave-uniform loop
        int n = e1 - e; if (n > 64) n = 64;
        int ce = e + lane; if (ce > e1 - 1) ce = e1 - 1;   // clamped coalesced index load
        int idx = csr[ce];
        int j = 0;
        for (; j + 8 <= n; j += 8) {      // independent 4B gathers in flight
          int s0 = __builtin_amdgcn_readlane(idx, j);
          int s1 = __builtin_amdgcn_readlane(idx, j + 1);
          int s2 = __builtin_amdgcn_readlane(idx, j + 2);
          int s3 = __builtin_amdgcn_readlane(idx, j + 3);
          int s4 = __builtin_amdgcn_readlane(idx, j + 4);
          int s5 = __builtin_amdgcn_readlane(idx, j + 5);
          int s6 = __builtin_amdgcn_readlane(idx, j + 6);
          int s7 = __builtin_amdgcn_readlane(idx, j + 7);
          unsigned u0 = *(const unsigned*)(feat + (size_t)s0 * F + vcol);
          unsigned u1 = *(const unsigned*)(feat + (size_t)s1 * F + vcol);
          unsigned u2 = *(const unsigned*)(feat + (size_t)s2 * F + vcol);
          unsigned u3 = *(const unsigned*)(feat + (size_t)s3 * F + vcol);
          unsigned u4 = *(const unsigned*)(feat + (size_t)s4 * F + vcol);
          unsigned u5 = *(const unsigned*)(feat + (size_t)s5 * F + vcol);
          unsigned u6 = *(const unsigned*)(feat + (size_t)s6 * F + vcol);
          unsigned u7 = *(const unsigned*)(feat + (size_t)s7 * F + vcol);
          ax += __uint_as_float(u0 << 16); ay += __uint_as_float(u0 & 0xffff0000u);
          ax += __uint_as_float(u1 << 16); ay += __uint_as_float(u1 & 0xffff0000u);
          ax += __uint_as_float(u2 << 16); ay += __uint_as_float(u2 & 0xffff0000u);
          ax += __uint_as_float(u3 << 16); ay += __uint_as_float(u3 & 0xffff0000u);
          ax += __uint_as_float(u4 << 16); ay += __uint_as_float(u4 & 0xffff0000u);
          ax += __uint_as_float(u5 << 16); ay += __uint_as_float(u5 & 0xffff0000u);
          ax += __uint_as_float(u6 << 16); ay += __uint_as_float(u6 & 0xffff0000u);
          ax += __uint_as_float(u7 << 16); ay += __uint_as_float(u7 & 0xffff0000u);
        }
        if (j + 4 <= n) {
          int s0 = __builtin_amdgcn_readlane(idx, j);
          int s1 = __builtin_amdgcn_readlane(idx, j + 1);
          int s2 = __builtin_amdgcn_readlane(idx, j + 2);
          int s3 = __builtin_amdgcn_readlane(idx, j + 3);
          unsigned u0 = *(const unsigned*)(feat + (size_t)s0 * F + vcol);
          unsigned u1 = *(const unsigned*)(feat + (size_t)s1 * F + vcol);
          unsigned u2 = *(const unsigned*)(feat + (size_t)s2 * F + vcol);
          unsigned u3 = *(const unsigned*)(feat + (size_t)s3 * F + vcol);
          ax += __uint_as_float(u0 << 16); ay += __uint_as_float(u0 & 0xffff0000u);
          ax += __uint_as_float(u1 << 16); ay += __uint_as_float(u1 & 0xffff0000u);
          ax += __uint_as_float(u2 << 16); ay += __uint_as_float(u2 & 0xffff0000u);
          ax += __uint_as_float(u3 << 16); ay += __uint_as_float(u3 & 0xffff0000u);
          j += 4;
        }
        for (; j < n; ++j) {
          int s0 = __builtin_amdgcn_readlane(idx, j);
          unsigned u0 = *(const unsigned*)(feat + (size_t)s0 * F + vcol);
          ax += __uint_as_float(u0 << 16); ay += __uint_as_float(u0 & 0xffff0000u);
        }
        e += n;
      }
    }
    sT[r][lane * 2]     = ax;
    sT[r][lane * 2 + 1] = ay;
  }
  __syncthreads();

  // Phase B: GEMM. Thread tile = 4 rows x 4 cols. W from global (L1/L2-resident).
  const int cg = t & 31, rg = t >> 5;
  const int c = cg * 4;
  const float4 b4 = *(const float4*)(bias + c);
  float4 a0 = b4, a1 = b4, a2 = b4, a3 = b4;
  const float4* __restrict__ W4 = (const float4*)W;
#pragma unroll 8
  for (int d = 0; d < DF; ++d) {
    float4 w = W4[d * (DF / 4) + cg];
    float x0 = sT[rg * 4 + 0][d];
    float x1 = sT[rg * 4 + 1][d];
    float x2 = sT[rg * 4 + 2][d];
    float x3 = sT[rg * 4 + 3][d];
    a0.x = fmaf(x0, w.x, a0.x); a0.y = fmaf(x0, w.y, a0.y);
    a0.z = fmaf(x0, w.z, a0.z); a0.w = fmaf(x0, w.w, a0.w);
    a1.x = fmaf(x1, w.x, a1.x); a1.y = fmaf(x1, w.y, a1.y);
    a1.z = fmaf(x1, w.z, a1.z); a1.w = fmaf(x1, w.w, a1.w);
    a2.x = fmaf(x2, w.x, a2.x); a2.y = fmaf(x2, w.y, a2.y);
    a2.z = fmaf(x2, w.z, a2.z); a2.w = fmaf(x2, w.w, a2.w);
    a3.x = fmaf(x3, w.x, a3.x); a3.y = fmaf(x3, w.y, a3.y);
    a3.z = fmaf(x3, w.z, a3.z); a3.w = fmaf(x3, w.w, a3.w);
  }

  const int nodeb = row0 + rg * 4;
  if (OUT_BF16) {
    ushort* ob = (ushort*)outp;
    float4 r4[4] = {relu4(a0), relu4(a1), relu4(a2), relu4(a3)};
#pragma unroll
    for (int k = 0; k < 4; ++k) {
      if (nodeb + k < NN) {
        ushort4 u;
        u.x = f2bf(r4[k].x); u.y = f2bf(r4[k].y); u.z = f2bf(r4[k].z); u.w = f2bf(r4[k].w);
        *(ushort4*)(ob + (size_t)(nodeb + k) * F + v * DF + c) = u;
      }
    }
  } else {
    float* of = (float*)outp;
    if (nodeb + 0 < NN) *(float4*)(of + (size_t)(nodeb + 0) * F + v * DF + c) = relu4(a0);
    if (nodeb + 1 < NN) *(float4*)(of + (size_t)(nodeb + 1) * F + v * DF + c) = relu4(a1);
    if (nodeb + 2 < NN) *(float4*)(of + (size_t)(nodeb + 2) * F + v * DF + c) = relu4(a2);
    if (nodeb + 3 < NN) *(float4*)(of + (size_t)(nodeb + 3) * F + v * DF + c) = relu4(a3);
  }
}

// ---------------- launch ----------------

static inline size_t align_up(size_t x, size_t a) { return (x + a - 1) & ~(a - 1); }

extern "C" void kernel_launch(void* const* d_in, const int* in_sizes, int n_in,
                              void* d_out, int out_size, void* d_ws, size_t ws_size,
                              hipStream_t stream) {
  const float* h   = (const float*)d_in[0];
  const int*   src = (const int*)d_in[1];
  const int*   dst = (const int*)d_in[2];
  const float* W1  = (const float*)d_in[3];
  const float* b1  = (const float*)d_in[4];
  const float* W2  = (const float*)d_in[5];
  const float* b2  = (const float*)d_in[6];
  float* out = (float*)d_out;

  // Workspace layout
  char* ws = (char*)d_ws;
  size_t o = 0;
  int* deg  = (int*)(ws + o); o = align_up(o + (size_t)NN * 4, 1024);
  int* cur  = (int*)(ws + o); o = align_up(o + (size_t)NN * 4, 1024);        // scatter cursor
  int* offs = (int*)(ws + o); o = align_up(o + (size_t)(NN + 1) * 4, 1024);
  int* bsum = (int*)(ws + o); o = align_up(o + 1024, 1024);
  int* csr  = (int*)(ws + o); o = align_up(o + (size_t)NE * 4, 1024);
  ushort* hb   = (ushort*)(ws + o); o = align_up(o + (size_t)NN * F * 2, 1024);  // bf16 h
  ushort* ybuf = (ushort*)(ws + o); o = align_up(o + (size_t)NN * F * 2, 1024);  // bf16 y
  (void)ws_size; (void)n_in; (void)in_sizes; (void)out_size;

  // CSR build + bf16 conversion
  hipMemsetAsync(deg, 0, (size_t)NN * 4, stream);
  k_count<<<1024, 256, 0, stream>>>(dst, deg);
  k_blocksum<<<NB, 256, 0, stream>>>(deg, bsum);
  k_scanb<<<1, 64, 0, stream>>>(bsum, NB, offs + NN);
  k_offsets<<<NB, 256, 0, stream>>>(deg, bsum, offs, cur);
  k_scatter<<<1024, 256, 0, stream>>>(src, dst, offs, cur, csr);
  k_tobf16<<<2048, 256, 0, stream>>>(h, hb, NN * F / 4);

  // Two fused layers: layer1 per-view W1/b1 (bf16 out), layer2 shared W2/b2 (fp32 out)
  dim3 grid((NN + TR - 1) / TR, NV);
  k_layer<true ><<<grid, 256, 0, stream>>>(hb,   offs, csr, W1, b1, DF * DF, DF, ybuf);
  k_layer<false><<<grid, 256, 0, stream>>>(ybuf, offs, csr, W2, b2, 0,       0,  out);
}

// Round 8
// 227.875 us; speedup vs baseline: 1.9213x; 1.6864x over previous
//
#include <hip/hip_runtime.h>

// Problem constants (from reference)
constexpr int NN = 50000;     // nodes
constexpr int NE = 400000;    // edges
constexpr int NV = 3;         // views
constexpr int DF = 128;       // per-view width
constexpr int F  = 384;       // total feature width (NV*DF)
constexpr int TR = 32;        // node rows per block tile
constexpr int NB = (NN + 255) / 256;  // 196 scan blocks
constexpr int SP = 136;       // sT row stride in ushort (+8 pad -> banks spread, 16B aligned)

typedef short  bf16x8 __attribute__((ext_vector_type(8)));
typedef float  f32x4  __attribute__((ext_vector_type(4)));

// ---------------- CSR build (by destination) ----------------

__global__ void k_count(const int* __restrict__ dst, int* __restrict__ deg) {
  int i = blockIdx.x * blockDim.x + threadIdx.x;
  int stride = gridDim.x * blockDim.x;
  for (int e = i; e < NE; e += stride) atomicAdd(&deg[dst[e]], 1);
}

__global__ void k_blocksum(const int* __restrict__ deg, int* __restrict__ bsum) {
  __shared__ int s[4];
  int i = blockIdx.x * 256 + threadIdx.x;
  int v = (i < NN) ? deg[i] : 0;
  for (int o = 32; o > 0; o >>= 1) v += __shfl_down(v, o);  // wave64 reduce
  if ((threadIdx.x & 63) == 0) s[threadIdx.x >> 6] = v;
  __syncthreads();
  if (threadIdx.x == 0) bsum[blockIdx.x] = s[0] + s[1] + s[2] + s[3];
}

__global__ void k_scanb(int* __restrict__ bsum, int nb, int* __restrict__ offs_n) {
  if (threadIdx.x == 0 && blockIdx.x == 0) {
    int run = 0;
    for (int i = 0; i < nb; ++i) { int v = bsum[i]; bsum[i] = run; run += v; }
    *offs_n = run;  // offs[NN] = NE
  }
}

__global__ void k_offsets(const int* __restrict__ deg, const int* __restrict__ bsum,
                          int* __restrict__ offs, int* __restrict__ cur) {
  __shared__ int s[256];
  int t = threadIdx.x;
  int i = blockIdx.x * 256 + t;
  int v = (i < NN) ? deg[i] : 0;
  s[t] = v;
  __syncthreads();
  for (int o = 1; o < 256; o <<= 1) {     // Hillis-Steele inclusive scan
    int add = (t >= o) ? s[t - o] : 0;
    __syncthreads();
    s[t] += add;
    __syncthreads();
  }
  if (i < NN) {
    offs[i] = bsum[blockIdx.x] + s[t] - v;  // exclusive
    cur[i] = 0;                              // zero scatter cursor
  }
}

__global__ void k_scatter(const int* __restrict__ src, const int* __restrict__ dst,
                          const int* __restrict__ offs, int* __restrict__ cnt,
                          int* __restrict__ csr) {
  int i = blockIdx.x * blockDim.x + threadIdx.x;
  int stride = gridDim.x * blockDim.x;
  for (int e = i; e < NE; e += stride) {
    int d = dst[e];
    int pos = offs[d] + atomicAdd(&cnt[d], 1);
    csr[pos] = src[e];
  }
}

// ---------------- bf16 helpers ----------------

__device__ __forceinline__ ushort f2bf(float f) {
  unsigned u = __float_as_uint(f);
  u = (u + 0x7fffu + ((u >> 16) & 1u)) >> 16;   // round-nearest-even
  return (ushort)u;
}

__global__ void k_tobf16(const float* __restrict__ in, ushort* __restrict__ outb, int n4) {
  int i = blockIdx.x * blockDim.x + threadIdx.x;
  int stride = gridDim.x * blockDim.x;
  const float4* in4 = (const float4*)in;
  for (int k = i; k < n4; k += stride) {
    float4 x = in4[k];
    ushort4 u;
    u.x = f2bf(x.x); u.y = f2bf(x.y); u.z = f2bf(x.z); u.w = f2bf(x.w);
    *(ushort4*)(outb + (size_t)k * 4) = u;
  }
}

// Pack W (fp32 [nv][DF][DF]) into MFMA B-fragment layout, hi/lo bf16 split.
// pk index: (((v*2+s)*4+kb)*8+cb)*512 + lane*8 + j
//   maps to W[v][ kb*32 + (lane>>4)*8 + j ][ cb*16 + (lane&15) ]
__global__ void k_wprep(const float* __restrict__ W, ushort* __restrict__ pk, int nv) {
  int idx = blockIdx.x * 256 + threadIdx.x;
  if (idx >= nv * 2 * 16384) return;
  int j = idx & 7, lane = (idx >> 3) & 63, cb = (idx >> 9) & 7, kb = (idx >> 12) & 3;
  int vs = idx >> 14;
  int v = vs >> 1, s = vs & 1;
  int d = kb * 32 + (lane >> 4) * 8 + j;
  int c = cb * 16 + (lane & 15);
  float w = W[((size_t)v * DF + d) * DF + c];
  ushort hi = f2bf(w);
  ushort outv = hi;
  if (s) {
    float rem = w - __uint_as_float((unsigned)hi << 16);
    outv = f2bf(rem);
  }
  pk[idx] = outv;
}

// ---------------- Fused aggregate + MFMA-GEMM(+bias+ReLU) layer ----------------
// Phase A: bf16 gather/fp32 accumulate (R5 structure, unchanged).
// sT stored as bf16 hi/lo split -> phase B: 3-term MFMA (AhiWhi+AloWhi+AhiWlo)
// gives ~fp32 GEMM precision at ~1/20 the VALU issue cost.

template <bool OUT_BF16>
__global__ __launch_bounds__(256, 4)
void k_layer(const ushort* __restrict__ feat,      // bf16 features [NN][F]
             const int* __restrict__ offs, const int* __restrict__ csr,
             const ushort* __restrict__ Wpk, int vmul,
             const float* __restrict__ ball, int bstride,
             void* __restrict__ outp) {
  __shared__ ushort sThi[TR][SP];   // 8.7 KB
  __shared__ ushort sTlo[TR][SP];   // 8.7 KB
  const int t = threadIdx.x;
  const int v = blockIdx.y;
  const float* __restrict__ bias = ball + (size_t)v * bstride;

  const int wave = t >> 6, lane = t & 63;
  const int lane15 = lane & 15, lgrp = lane >> 4;
  const int row0 = blockIdx.x * TR;
  const int vcol = v * DF + lane * 2;   // element offset within feature row
  const int lane2 = lane * 2;

  // ---- Phase A: aggregate (one wave per node-row, 8 rows/wave) ----
#pragma unroll
  for (int rr = 0; rr < TR / 4; ++rr) {
    int r = rr * 4 + wave;
    int node = row0 + r;
    float ax = 0.f, ay = 0.f;
    if (node < NN) {
      int e0 = offs[node], e1 = offs[node + 1];
      int e = e0;
      while (e < e1) {                    // wave-uniform loop
        int n = e1 - e; if (n > 64) n = 64;
        int ce = e + lane; if (ce > e1 - 1) ce = e1 - 1;
        int idx = csr[ce];
        int j = 0;
        for (; j + 8 <= n; j += 8) {
          int s0 = __builtin_amdgcn_readlane(idx, j);
          int s1 = __builtin_amdgcn_readlane(idx, j + 1);
          int s2 = __builtin_amdgcn_readlane(idx, j + 2);
          int s3 = __builtin_amdgcn_readlane(idx, j + 3);
          int s4 = __builtin_amdgcn_readlane(idx, j + 4);
          int s5 = __builtin_amdgcn_readlane(idx, j + 5);
          int s6 = __builtin_amdgcn_readlane(idx, j + 6);
          int s7 = __builtin_amdgcn_readlane(idx, j + 7);
          unsigned u0 = *(const unsigned*)(feat + (size_t)s0 * F + vcol);
          unsigned u1 = *(const unsigned*)(feat + (size_t)s1 * F + vcol);
          unsigned u2 = *(const unsigned*)(feat + (size_t)s2 * F + vcol);
          unsigned u3 = *(const unsigned*)(feat + (size_t)s3 * F + vcol);
          unsigned u4 = *(const unsigned*)(feat + (size_t)s4 * F + vcol);
          unsigned u5 = *(const unsigned*)(feat + (size_t)s5 * F + vcol);
          unsigned u6 = *(const unsigned*)(feat + (size_t)s6 * F + vcol);
          unsigned u7 = *(const unsigned*)(feat + (size_t)s7 * F + vcol);
          ax += __uint_as_float(u0 << 16); ay += __uint_as_float(u0 & 0xffff0000u);
          ax += __uint_as_float(u1 << 16); ay += __uint_as_float(u1 & 0xffff0000u);
          ax += __uint_as_float(u2 << 16); ay += __uint_as_float(u2 & 0xffff0000u);
          ax += __uint_as_float(u3 << 16); ay += __uint_as_float(u3 & 0xffff0000u);
          ax += __uint_as_float(u4 << 16); ay += __uint_as_float(u4 & 0xffff0000u);
          ax += __uint_as_float(u5 << 16); ay += __uint_as_float(u5 & 0xffff0000u);
          ax += __uint_as_float(u6 << 16); ay += __uint_as_float(u6 & 0xffff0000u);
          ax += __uint_as_float(u7 << 16); ay += __uint_as_float(u7 & 0xffff0000u);
        }
        if (j + 4 <= n) {
          int s0 = __builtin_amdgcn_readlane(idx, j);
          int s1 = __builtin_amdgcn_readlane(idx, j + 1);
          int s2 = __builtin_amdgcn_readlane(idx, j + 2);
          int s3 = __builtin_amdgcn_readlane(idx, j + 3);
          unsigned u0 = *(const unsigned*)(feat + (size_t)s0 * F + vcol);
          unsigned u1 = *(const unsigned*)(feat + (size_t)s1 * F + vcol);
          unsigned u2 = *(const unsigned*)(feat + (size_t)s2 * F + vcol);
          unsigned u3 = *(const unsigned*)(feat + (size_t)s3 * F + vcol);
          ax += __uint_as_float(u0 << 16); ay += __uint_as_float(u0 & 0xffff0000u);
          ax += __uint_as_float(u1 << 16); ay += __uint_as_float(u1 & 0xffff0000u);
          ax += __uint_as_float(u2 << 16); ay += __uint_as_float(u2 & 0xffff0000u);
          ax += __uint_as_float(u3 << 16); ay += __uint_as_float(u3 & 0xffff0000u);
          j += 4;
        }
        for (; j < n; ++j) {
          int s0 = __builtin_amdgcn_readlane(idx, j);
          unsigned u0 = *(const unsigned*)(feat + (size_t)s0 * F + vcol);
          ax += __uint_as_float(u0 << 16); ay += __uint_as_float(u0 & 0xffff0000u);
        }
        e += n;
      }
    }
    // hi/lo split of fp32 aggregate -> 2x bf16 arrays
    ushort hx = f2bf(ax);
    ushort lx = f2bf(ax - __uint_as_float((unsigned)hx << 16));
    ushort hy = f2bf(ay);
    ushort ly = f2bf(ay - __uint_as_float((unsigned)hy << 16));
    *(unsigned*)&sThi[r][lane2] = (unsigned)hx | ((unsigned)hy << 16);
    *(unsigned*)&sTlo[r][lane2] = (unsigned)lx | ((unsigned)ly << 16);
  }
  __syncthreads();

  // ---- Phase B: MFMA GEMM. Wave w -> col-blocks 2w,2w+1; row-blocks 0,1. ----
  const ushort* pkbase = Wpk + (size_t)(v * vmul) * (2 * 4 * 8 * 512);
  const float bv0 = bias[wave * 32 + lane15];
  const float bv1 = bias[wave * 32 + 16 + lane15];
  f32x4 acc00 = {bv0, bv0, bv0, bv0};
  f32x4 acc01 = {bv1, bv1, bv1, bv1};
  f32x4 acc10 = {bv0, bv0, bv0, bv0};
  f32x4 acc11 = {bv1, bv1, bv1, bv1};

#pragma unroll
  for (int kb = 0; kb < 4; ++kb) {
    const int acol = kb * 32 + lgrp * 8;
    bf16x8 ah0 = *(const bf16x8*)&sThi[lane15][acol];
    bf16x8 ah1 = *(const bf16x8*)&sThi[16 + lane15][acol];
    bf16x8 al0 = *(const bf16x8*)&sTlo[lane15][acol];
    bf16x8 al1 = *(const bf16x8*)&sTlo[16 + lane15][acol];
    bf16x8 bh0 = *(const bf16x8*)(pkbase + ((size_t)((0 * 4 + kb) * 8 + wave * 2 + 0)) * 512 + lane * 8);
    bf16x8 bh1 = *(const bf16x8*)(pkbase + ((size_t)((0 * 4 + kb) * 8 + wave * 2 + 1)) * 512 + lane * 8);
    bf16x8 bl0 = *(const bf16x8*)(pkbase + ((size_t)((1 * 4 + kb) * 8 + wave * 2 + 0)) * 512 + lane * 8);
    bf16x8 bl1 = *(const bf16x8*)(pkbase + ((size_t)((1 * 4 + kb) * 8 + wave * 2 + 1)) * 512 + lane * 8);
    acc00 = __builtin_amdgcn_mfma_f32_16x16x32_bf16(ah0, bh0, acc00, 0, 0, 0);
    acc00 = __builtin_amdgcn_mfma_f32_16x16x32_bf16(al0, bh0, acc00, 0, 0, 0);
    acc00 = __builtin_amdgcn_mfma_f32_16x16x32_bf16(ah0, bl0, acc00, 0, 0, 0);
    acc01 = __builtin_amdgcn_mfma_f32_16x16x32_bf16(ah0, bh1, acc01, 0, 0, 0);
    acc01 = __builtin_amdgcn_mfma_f32_16x16x32_bf16(al0, bh1, acc01, 0, 0, 0);
    acc01 = __builtin_amdgcn_mfma_f32_16x16x32_bf16(ah0, bl1, acc01, 0, 0, 0);
    acc10 = __builtin_amdgcn_mfma_f32_16x16x32_bf16(ah1, bh0, acc10, 0, 0, 0);
    acc10 = __builtin_amdgcn_mfma_f32_16x16x32_bf16(al1, bh0, acc10, 0, 0, 0);
    acc10 = __builtin_amdgcn_mfma_f32_16x16x32_bf16(ah1, bl0, acc10, 0, 0, 0);
    acc11 = __builtin_amdgcn_mfma_f32_16x16x32_bf16(ah1, bh1, acc11, 0, 0, 0);
    acc11 = __builtin_amdgcn_mfma_f32_16x16x32_bf16(al1, bh1, acc11, 0, 0, 0);
    acc11 = __builtin_amdgcn_mfma_f32_16x16x32_bf16(ah1, bl1, acc11, 0, 0, 0);
  }

  // ---- Epilogue: relu + store. C/D: col=lane&15, row=(lane>>4)*4+reg ----
  const int colbase = v * DF + wave * 32 + lane15;
#pragma unroll
  for (int rb = 0; rb < 2; ++rb) {
    f32x4 a0 = rb ? acc10 : acc00;
    f32x4 a1 = rb ? acc11 : acc01;
#pragma unroll
    for (int k = 0; k < 4; ++k) {
      int row = row0 + rb * 16 + lgrp * 4 + k;
      if (row < NN) {
        float x0 = a0[k] > 0.f ? a0[k] : 0.f;
        float x1 = a1[k] > 0.f ? a1[k] : 0.f;
        if (OUT_BF16) {
          ushort* ob = (ushort*)outp;
          ob[(size_t)row * F + colbase]      = f2bf(x0);
          ob[(size_t)row * F + colbase + 16] = f2bf(x1);
        } else {
          float* of = (float*)outp;
          of[(size_t)row * F + colbase]      = x0;
          of[(size_t)row * F + colbase + 16] = x1;
        }
      }
    }
  }
}

// ---------------- launch ----------------

static inline size_t align_up(size_t x, size_t a) { return (x + a - 1) & ~(a - 1); }

extern "C" void kernel_launch(void* const* d_in, const int* in_sizes, int n_in,
                              void* d_out, int out_size, void* d_ws, size_t ws_size,
                              hipStream_t stream) {
  const float* h   = (const float*)d_in[0];
  const int*   src = (const int*)d_in[1];
  const int*   dst = (const int*)d_in[2];
  const float* W1  = (const float*)d_in[3];
  const float* b1  = (const float*)d_in[4];
  const float* W2  = (const float*)d_in[5];
  const float* b2  = (const float*)d_in[6];
  float* out = (float*)d_out;

  // Workspace layout
  char* ws = (char*)d_ws;
  size_t o = 0;
  int* deg  = (int*)(ws + o); o = align_up(o + (size_t)NN * 4, 1024);
  int* cur  = (int*)(ws + o); o = align_up(o + (size_t)NN * 4, 1024);
  int* offs = (int*)(ws + o); o = align_up(o + (size_t)(NN + 1) * 4, 1024);
  int* bsum = (int*)(ws + o); o = align_up(o + 1024, 1024);
  int* csr  = (int*)(ws + o); o = align_up(o + (size_t)NE * 4, 1024);
  ushort* hb   = (ushort*)(ws + o); o = align_up(o + (size_t)NN * F * 2, 1024);  // bf16 h
  ushort* ybuf = (ushort*)(ws + o); o = align_up(o + (size_t)NN * F * 2, 1024);  // bf16 y
  ushort* w1pk = (ushort*)(ws + o); o = align_up(o + (size_t)NV * 2 * 16384 * 2, 1024);
  ushort* w2pk = (ushort*)(ws + o); o = align_up(o + (size_t)1 * 2 * 16384 * 2, 1024);
  (void)ws_size; (void)n_in; (void)in_sizes; (void)out_size;

  // CSR build + bf16 conversion + W packing
  hipMemsetAsync(deg, 0, (size_t)NN * 4, stream);
  k_count<<<1024, 256, 0, stream>>>(dst, deg);
  k_blocksum<<<NB, 256, 0, stream>>>(deg, bsum);
  k_scanb<<<1, 64, 0, stream>>>(bsum, NB, offs + NN);
  k_offsets<<<NB, 256, 0, stream>>>(deg, bsum, offs, cur);
  k_scatter<<<1024, 256, 0, stream>>>(src, dst, offs, cur, csr);
  k_tobf16<<<2048, 256, 0, stream>>>(h, hb, NN * F / 4);
  k_wprep<<<(NV * 2 * 16384) / 256, 256, 0, stream>>>(W1, w1pk, NV);
  k_wprep<<<(2 * 16384) / 256, 256, 0, stream>>>(W2, w2pk, 1);

  // Two fused layers
  dim3 grid((NN + TR - 1) / TR, NV);
  k_layer<true ><<<grid, 256, 0, stream>>>(hb,   offs, csr, w1pk, 1, b1, DF, ybuf);
  k_layer<false><<<grid, 256, 0, stream>>>(ybuf, offs, csr, w2pk, 0, b2, 0,  out);
}

// Round 9
// 203.148 us; speedup vs baseline: 2.1552x; 1.1217x over previous
//
#include <hip/hip_runtime.h>

// Problem constants (from reference)
constexpr int NN = 50000;     // nodes
constexpr int NE = 400000;    // edges
constexpr int NV = 3;         // views
constexpr int DF = 128;       // per-view width
constexpr int F  = 384;       // total feature width (NV*DF)
constexpr int TR = 32;        // node rows per block tile
constexpr int NB = (NN + 255) / 256;  // 196 scan blocks
constexpr int SP = 136;       // sT row stride in ushort (+8 pad, 16B aligned)

typedef short  bf16x8 __attribute__((ext_vector_type(8)));
typedef float  f32x4  __attribute__((ext_vector_type(4)));

// ---------------- bf16 helpers ----------------

__device__ __forceinline__ ushort f2bf(float f) {
  unsigned u = __float_as_uint(f);
  u = (u + 0x7fffu + ((u >> 16) & 1u)) >> 16;   // round-nearest-even
  return (ushort)u;
}

// ---------------- fused prep 0: W1 pack || W2 pack || deg zero ----------------
// W pack layout: pk[(((v*2+s)*4+kb)*8+cb)*512 + lane*8 + j]
//   = bf16_{hi,lo}( W[v][ kb*32 + (lane>>4)*8 + j ][ cb*16 + (lane&15) ] )

__device__ __forceinline__ void wprep_one(const float* __restrict__ W,
                                          ushort* __restrict__ pk, int idx) {
  int j = idx & 7, lane = (idx >> 3) & 63, cb = (idx >> 9) & 7, kb = (idx >> 12) & 3;
  int vs = idx >> 14;
  int v = vs >> 1, s = vs & 1;
  int d = kb * 32 + (lane >> 4) * 8 + j;
  int c = cb * 16 + (lane & 15);
  float w = W[((size_t)v * DF + d) * DF + c];
  ushort hi = f2bf(w);
  ushort outv = hi;
  if (s) outv = f2bf(w - __uint_as_float((unsigned)hi << 16));
  pk[idx] = outv;
}

constexpr int WB1 = (NV * 2 * 16384) / 256;   // 384 blocks
constexpr int WB2 = (2 * 16384) / 256;        // 128 blocks

__global__ void k_prep0(const float* __restrict__ W1, const float* __restrict__ W2,
                        ushort* __restrict__ w1pk, ushort* __restrict__ w2pk,
                        int* __restrict__ deg) {
  int b = blockIdx.x, t = threadIdx.x;
  if (b < WB1) {
    wprep_one(W1, w1pk, b * 256 + t);
  } else if (b < WB1 + WB2) {
    wprep_one(W2, w2pk, (b - WB1) * 256 + t);
  } else {
    int i = (b - WB1 - WB2) * 256 + t;
    if (i < NN) deg[i] = 0;
  }
}

// ---------------- fused prep 1: h -> bf16 convert || edge count ----------------

__global__ void k_cvtcnt(const float* __restrict__ in, ushort* __restrict__ outb,
                         const int* __restrict__ dst, int* __restrict__ deg) {
  int b = blockIdx.x, t = threadIdx.x;
  if (b < 2048) {
    const int n4 = NN * F / 4;
    const float4* in4 = (const float4*)in;
    for (int k = b * 256 + t; k < n4; k += 2048 * 256) {
      float4 x = in4[k];
      ushort4 u;
      u.x = f2bf(x.x); u.y = f2bf(x.y); u.z = f2bf(x.z); u.w = f2bf(x.w);
      *(ushort4*)(outb + (size_t)k * 4) = u;
    }
  } else {
    for (int e = (b - 2048) * 256 + t; e < NE; e += 1024 * 256)
      atomicAdd(&deg[dst[e]], 1);
  }
}

// ---------------- CSR build (by destination) ----------------

__global__ void k_blocksum(const int* __restrict__ deg, int* __restrict__ bsum) {
  __shared__ int s[4];
  int i = blockIdx.x * 256 + threadIdx.x;
  int v = (i < NN) ? deg[i] : 0;
  for (int o = 32; o > 0; o >>= 1) v += __shfl_down(v, o);  // wave64 reduce
  if ((threadIdx.x & 63) == 0) s[threadIdx.x >> 6] = v;
  __syncthreads();
  if (threadIdx.x == 0) bsum[blockIdx.x] = s[0] + s[1] + s[2] + s[3];
}

// parallel one-block exclusive scan over NB block sums (replaces serial k_scanb)
__global__ void k_scanpar(int* __restrict__ bsum, int* __restrict__ offs_n) {
  __shared__ int s[256];
  int t = threadIdx.x;
  int v = (t < NB) ? bsum[t] : 0;
  s[t] = v;
  __syncthreads();
  for (int o = 1; o < 256; o <<= 1) {
    int add = (t >= o) ? s[t - o] : 0;
    __syncthreads();
    s[t] += add;
    __syncthreads();
  }
  if (t < NB) bsum[t] = s[t] - v;      // exclusive
  if (t == NB - 1) *offs_n = s[t];     // offs[NN] = NE
}

__global__ void k_offsets(const int* __restrict__ deg, const int* __restrict__ bsum,
                          int* __restrict__ offs) {
  __shared__ int s[256];
  int t = threadIdx.x;
  int i = blockIdx.x * 256 + t;
  int v = (i < NN) ? deg[i] : 0;
  s[t] = v;
  __syncthreads();
  for (int o = 1; o < 256; o <<= 1) {     // Hillis-Steele inclusive scan
    int add = (t >= o) ? s[t - o] : 0;
    __syncthreads();
    s[t] += add;
    __syncthreads();
  }
  if (i < NN) offs[i] = bsum[blockIdx.x] + s[t] - v;  // exclusive
}

// scatter uses deg itself as a countdown cursor (deg dead afterwards)
__global__ void k_scatter(const int* __restrict__ src, const int* __restrict__ dst,
                          const int* __restrict__ offs, int* __restrict__ deg,
                          int* __restrict__ csr) {
  int i = blockIdx.x * blockDim.x + threadIdx.x;
  int stride = gridDim.x * blockDim.x;
  for (int e = i; e < NE; e += stride) {
    int d = dst[e];
    int pos = offs[d] + atomicSub(&deg[d], 1) - 1;
    csr[pos] = src[e];
  }
}

// ---------------- Fused aggregate + MFMA-GEMM(+bias+ReLU) layer ----------------
// Phase A: bf16 gather/fp32 accumulate. sT stored as bf16 hi/lo split.
// Phase B: 3-term MFMA (AhiWhi+AloWhi+AhiWlo) ~ fp32 GEMM precision.

template <bool OUT_BF16>
__global__ __launch_bounds__(256, 4)
void k_layer(const ushort* __restrict__ feat,      // bf16 features [NN][F]
             const int* __restrict__ offs, const int* __restrict__ csr,
             const ushort* __restrict__ Wpk, int vmul,
             const float* __restrict__ ball, int bstride,
             void* __restrict__ outp) {
  __shared__ ushort sThi[TR][SP];   // 8.7 KB
  __shared__ ushort sTlo[TR][SP];   // 8.7 KB
  const int t = threadIdx.x;
  const int v = blockIdx.y;
  const float* __restrict__ bias = ball + (size_t)v * bstride;

  const int wave = t >> 6, lane = t & 63;
  const int lane15 = lane & 15, lgrp = lane >> 4;
  const int row0 = blockIdx.x * TR;
  const int vcol = v * DF + lane * 2;   // element offset within feature row
  const int lane2 = lane * 2;

  // ---- Phase A: aggregate (one wave per node-row, 8 rows/wave) ----
#pragma unroll
  for (int rr = 0; rr < TR / 4; ++rr) {
    int r = rr * 4 + wave;
    int node = row0 + r;
    float ax = 0.f, ay = 0.f;
    if (node < NN) {
      int e0 = offs[node], e1 = offs[node + 1];
      int e = e0;
      while (e < e1) {                    // wave-uniform loop
        int n = e1 - e; if (n > 64) n = 64;
        int ce = e + lane; if (ce > e1 - 1) ce = e1 - 1;
        int idx = csr[ce];
        int j = 0;
        for (; j + 8 <= n; j += 8) {
          int s0 = __builtin_amdgcn_readlane(idx, j);
          int s1 = __builtin_amdgcn_readlane(idx, j + 1);
          int s2 = __builtin_amdgcn_readlane(idx, j + 2);
          int s3 = __builtin_amdgcn_readlane(idx, j + 3);
          int s4 = __builtin_amdgcn_readlane(idx, j + 4);
          int s5 = __builtin_amdgcn_readlane(idx, j + 5);
          int s6 = __builtin_amdgcn_readlane(idx, j + 6);
          int s7 = __builtin_amdgcn_readlane(idx, j + 7);
          unsigned u0 = *(const unsigned*)(feat + (size_t)s0 * F + vcol);
          unsigned u1 = *(const unsigned*)(feat + (size_t)s1 * F + vcol);
          unsigned u2 = *(const unsigned*)(feat + (size_t)s2 * F + vcol);
          unsigned u3 = *(const unsigned*)(feat + (size_t)s3 * F + vcol);
          unsigned u4 = *(const unsigned*)(feat + (size_t)s4 * F + vcol);
          unsigned u5 = *(const unsigned*)(feat + (size_t)s5 * F + vcol);
          unsigned u6 = *(const unsigned*)(feat + (size_t)s6 * F + vcol);
          unsigned u7 = *(const unsigned*)(feat + (size_t)s7 * F + vcol);
          ax += __uint_as_float(u0 << 16); ay += __uint_as_float(u0 & 0xffff0000u);
          ax += __uint_as_float(u1 << 16); ay += __uint_as_float(u1 & 0xffff0000u);
          ax += __uint_as_float(u2 << 16); ay += __uint_as_float(u2 & 0xffff0000u);
          ax += __uint_as_float(u3 << 16); ay += __uint_as_float(u3 & 0xffff0000u);
          ax += __uint_as_float(u4 << 16); ay += __uint_as_float(u4 & 0xffff0000u);
          ax += __uint_as_float(u5 << 16); ay += __uint_as_float(u5 & 0xffff0000u);
          ax += __uint_as_float(u6 << 16); ay += __uint_as_float(u6 & 0xffff0000u);
          ax += __uint_as_float(u7 << 16); ay += __uint_as_float(u7 & 0xffff0000u);
        }
        if (j + 4 <= n) {
          int s0 = __builtin_amdgcn_readlane(idx, j);
          int s1 = __builtin_amdgcn_readlane(idx, j + 1);
          int s2 = __builtin_amdgcn_readlane(idx, j + 2);
          int s3 = __builtin_amdgcn_readlane(idx, j + 3);
          unsigned u0 = *(const unsigned*)(feat + (size_t)s0 * F + vcol);
          unsigned u1 = *(const unsigned*)(feat + (size_t)s1 * F + vcol);
          unsigned u2 = *(const unsigned*)(feat + (size_t)s2 * F + vcol);
          unsigned u3 = *(const unsigned*)(feat + (size_t)s3 * F + vcol);
          ax += __uint_as_float(u0 << 16); ay += __uint_as_float(u0 & 0xffff0000u);
          ax += __uint_as_float(u1 << 16); ay += __uint_as_float(u1 & 0xffff0000u);
          ax += __uint_as_float(u2 << 16); ay += __uint_as_float(u2 & 0xffff0000u);
          ax += __uint_as_float(u3 << 16); ay += __uint_as_float(u3 & 0xffff0000u);
          j += 4;
        }
        for (; j < n; ++j) {
          int s0 = __builtin_amdgcn_readlane(idx, j);
          unsigned u0 = *(const unsigned*)(feat + (size_t)s0 * F + vcol);
          ax += __uint_as_float(u0 << 16); ay += __uint_as_float(u0 & 0xffff0000u);
        }
        e += n;
      }
    }
    // hi/lo split of fp32 aggregate -> 2x bf16 arrays
    ushort hx = f2bf(ax);
    ushort lx = f2bf(ax - __uint_as_float((unsigned)hx << 16));
    ushort hy = f2bf(ay);
    ushort ly = f2bf(ay - __uint_as_float((unsigned)hy << 16));
    *(unsigned*)&sThi[r][lane2] = (unsigned)hx | ((unsigned)hy << 16);
    *(unsigned*)&sTlo[r][lane2] = (unsigned)lx | ((unsigned)ly << 16);
  }
  __syncthreads();

  // ---- Phase B: MFMA GEMM. Wave w -> col-blocks 2w,2w+1; row-blocks 0,1. ----
  const ushort* pkbase = Wpk + (size_t)(v * vmul) * (2 * 4 * 8 * 512);
  const float bv0 = bias[wave * 32 + lane15];
  const float bv1 = bias[wave * 32 + 16 + lane15];
  f32x4 acc00 = {bv0, bv0, bv0, bv0};
  f32x4 acc01 = {bv1, bv1, bv1, bv1};
  f32x4 acc10 = {bv0, bv0, bv0, bv0};
  f32x4 acc11 = {bv1, bv1, bv1, bv1};

#pragma unroll
  for (int kb = 0; kb < 4; ++kb) {
    const int acol = kb * 32 + lgrp * 8;
    bf16x8 ah0 = *(const bf16x8*)&sThi[lane15][acol];
    bf16x8 ah1 = *(const bf16x8*)&sThi[16 + lane15][acol];
    bf16x8 al0 = *(const bf16x8*)&sTlo[lane15][acol];
    bf16x8 al1 = *(const bf16x8*)&sTlo[16 + lane15][acol];
    bf16x8 bh0 = *(const bf16x8*)(pkbase + ((size_t)((0 * 4 + kb) * 8 + wave * 2 + 0)) * 512 + lane * 8);
    bf16x8 bh1 = *(const bf16x8*)(pkbase + ((size_t)((0 * 4 + kb) * 8 + wave * 2 + 1)) * 512 + lane * 8);
    bf16x8 bl0 = *(const bf16x8*)(pkbase + ((size_t)((1 * 4 + kb) * 8 + wave * 2 + 0)) * 512 + lane * 8);
    bf16x8 bl1 = *(const bf16x8*)(pkbase + ((size_t)((1 * 4 + kb) * 8 + wave * 2 + 1)) * 512 + lane * 8);
    acc00 = __builtin_amdgcn_mfma_f32_16x16x32_bf16(ah0, bh0, acc00, 0, 0, 0);
    acc00 = __builtin_amdgcn_mfma_f32_16x16x32_bf16(al0, bh0, acc00, 0, 0, 0);
    acc00 = __builtin_amdgcn_mfma_f32_16x16x32_bf16(ah0, bl0, acc00, 0, 0, 0);
    acc01 = __builtin_amdgcn_mfma_f32_16x16x32_bf16(ah0, bh1, acc01, 0, 0, 0);
    acc01 = __builtin_amdgcn_mfma_f32_16x16x32_bf16(al0, bh1, acc01, 0, 0, 0);
    acc01 = __builtin_amdgcn_mfma_f32_16x16x32_bf16(ah0, bl1, acc01, 0, 0, 0);
    acc10 = __builtin_amdgcn_mfma_f32_16x16x32_bf16(ah1, bh0, acc10, 0, 0, 0);
    acc10 = __builtin_amdgcn_mfma_f32_16x16x32_bf16(al1, bh0, acc10, 0, 0, 0);
    acc10 = __builtin_amdgcn_mfma_f32_16x16x32_bf16(ah1, bl0, acc10, 0, 0, 0);
    acc11 = __builtin_amdgcn_mfma_f32_16x16x32_bf16(ah1, bh1, acc11, 0, 0, 0);
    acc11 = __builtin_amdgcn_mfma_f32_16x16x32_bf16(al1, bh1, acc11, 0, 0, 0);
    acc11 = __builtin_amdgcn_mfma_f32_16x16x32_bf16(ah1, bl1, acc11, 0, 0, 0);
  }

  // ---- Epilogue: relu + store. C/D: col=lane&15, row=(lane>>4)*4+reg ----
  const int colbase = v * DF + wave * 32 + lane15;
#pragma unroll
  for (int rb = 0; rb < 2; ++rb) {
    f32x4 a0 = rb ? acc10 : acc00;
    f32x4 a1 = rb ? acc11 : acc01;
#pragma unroll
    for (int k = 0; k < 4; ++k) {
      int row = row0 + rb * 16 + lgrp * 4 + k;
      if (row < NN) {
        float x0 = a0[k] > 0.f ? a0[k] : 0.f;
        float x1 = a1[k] > 0.f ? a1[k] : 0.f;
        if (OUT_BF16) {
          ushort* ob = (ushort*)outp;
          ob[(size_t)row * F + colbase]      = f2bf(x0);
          ob[(size_t)row * F + colbase + 16] = f2bf(x1);
        } else {
          float* of = (float*)outp;
          of[(size_t)row * F + colbase]      = x0;
          of[(size_t)row * F + colbase + 16] = x1;
        }
      }
    }
  }
}

// ---------------- launch ----------------

static inline size_t align_up(size_t x, size_t a) { return (x + a - 1) & ~(a - 1); }

extern "C" void kernel_launch(void* const* d_in, const int* in_sizes, int n_in,
                              void* d_out, int out_size, void* d_ws, size_t ws_size,
                              hipStream_t stream) {
  const float* h   = (const float*)d_in[0];
  const int*   src = (const int*)d_in[1];
  const int*   dst = (const int*)d_in[2];
  const float* W1  = (const float*)d_in[3];
  const float* b1  = (const float*)d_in[4];
  const float* W2  = (const float*)d_in[5];
  const float* b2  = (const float*)d_in[6];
  float* out = (float*)d_out;

  // Workspace layout
  char* ws = (char*)d_ws;
  size_t o = 0;
  int* deg  = (int*)(ws + o); o = align_up(o + (size_t)NN * 4, 1024);
  int* offs = (int*)(ws + o); o = align_up(o + (size_t)(NN + 1) * 4, 1024);
  int* bsum = (int*)(ws + o); o = align_up(o + 1024, 1024);
  int* csr  = (int*)(ws + o); o = align_up(o + (size_t)NE * 4, 1024);
  ushort* hb   = (ushort*)(ws + o); o = align_up(o + (size_t)NN * F * 2, 1024);  // bf16 h
  ushort* ybuf = (ushort*)(ws + o); o = align_up(o + (size_t)NN * F * 2, 1024);  // bf16 y
  ushort* w1pk = (ushort*)(ws + o); o = align_up(o + (size_t)NV * 2 * 16384 * 2, 1024);
  ushort* w2pk = (ushort*)(ws + o); o = align_up(o + (size_t)1 * 2 * 16384 * 2, 1024);
  (void)ws_size; (void)n_in; (void)in_sizes; (void)out_size;

  // Prep: 8 dispatches total (was 10; serial scan removed)
  k_prep0<<<WB1 + WB2 + NB, 256, 0, stream>>>(W1, W2, w1pk, w2pk, deg);
  k_cvtcnt<<<3072, 256, 0, stream>>>(h, hb, dst, deg);
  k_blocksum<<<NB, 256, 0, stream>>>(deg, bsum);
  k_scanpar<<<1, 256, 0, stream>>>(bsum, offs + NN);
  k_offsets<<<NB, 256, 0, stream>>>(deg, bsum, offs);
  k_scatter<<<1024, 256, 0, stream>>>(src, dst, offs, deg, csr);

  // Two fused layers
  dim3 grid((NN + TR - 1) / TR, NV);
  k_layer<true ><<<grid, 256, 0, stream>>>(hb,   offs, csr, w1pk, 1, b1, DF, ybuf);
  k_layer<false><<<grid, 256, 0, stream>>>(ybuf, offs, csr, w2pk, 0, b2, 0,  out);
}

// Round 10
// 195.924 us; speedup vs baseline: 2.2346x; 1.0369x over previous
//
#include <hip/hip_runtime.h>

// Problem constants (from reference)
constexpr int NN = 50000;     // nodes
constexpr int NE = 400000;    // edges
constexpr int NV = 3;         // views
constexpr int DF = 128;       // per-view width
constexpr int F  = 384;       // total feature width (NV*DF)
constexpr int TR = 32;        // node rows per block tile
constexpr int NB = (NN + 255) / 256;  // 196 scan blocks
constexpr int SP = 136;       // sT row stride in ushort (+8 pad, 16B aligned)

typedef short  bf16x8 __attribute__((ext_vector_type(8)));
typedef float  f32x4  __attribute__((ext_vector_type(4)));

// ---------------- bf16 helpers ----------------

__device__ __forceinline__ ushort f2bf(float f) {
  unsigned u = __float_as_uint(f);
  u = (u + 0x7fffu + ((u >> 16) & 1u)) >> 16;   // round-nearest-even
  return (ushort)u;
}

// ---------------- fused prep 0: W1 pack || W2 pack || deg zero ----------------
// W pack layout: pk[(((v*2+s)*4+kb)*8+cb)*512 + lane*8 + j]
//   = bf16_{hi,lo}( W[v][ kb*32 + (lane>>4)*8 + j ][ cb*16 + (lane&15) ] )

__device__ __forceinline__ void wprep_one(const float* __restrict__ W,
                                          ushort* __restrict__ pk, int idx) {
  int j = idx & 7, lane = (idx >> 3) & 63, cb = (idx >> 9) & 7, kb = (idx >> 12) & 3;
  int vs = idx >> 14;
  int v = vs >> 1, s = vs & 1;
  int d = kb * 32 + (lane >> 4) * 8 + j;
  int c = cb * 16 + (lane & 15);
  float w = W[((size_t)v * DF + d) * DF + c];
  ushort hi = f2bf(w);
  ushort outv = hi;
  if (s) outv = f2bf(w - __uint_as_float((unsigned)hi << 16));
  pk[idx] = outv;
}

constexpr int WB1 = (NV * 2 * 16384) / 256;   // 384 blocks
constexpr int WB2 = (2 * 16384) / 256;        // 128 blocks

__global__ void k_prep0(const float* __restrict__ W1, const float* __restrict__ W2,
                        ushort* __restrict__ w1pk, ushort* __restrict__ w2pk,
                        int* __restrict__ deg) {
  int b = blockIdx.x, t = threadIdx.x;
  if (b < WB1) {
    wprep_one(W1, w1pk, b * 256 + t);
  } else if (b < WB1 + WB2) {
    wprep_one(W2, w2pk, (b - WB1) * 256 + t);
  } else {
    int i = (b - WB1 - WB2) * 256 + t;
    if (i < NN) deg[i] = 0;
  }
}

// ---------------- fused prep 1: h -> bf16 convert || edge count ----------------

__global__ void k_cvtcnt(const float* __restrict__ in, ushort* __restrict__ outb,
                         const int* __restrict__ dst, int* __restrict__ deg) {
  int b = blockIdx.x, t = threadIdx.x;
  if (b < 2048) {
    const int n4 = NN * F / 4;
    const float4* in4 = (const float4*)in;
    for (int k = b * 256 + t; k < n4; k += 2048 * 256) {
      float4 x = in4[k];
      ushort4 u;
      u.x = f2bf(x.x); u.y = f2bf(x.y); u.z = f2bf(x.z); u.w = f2bf(x.w);
      *(ushort4*)(outb + (size_t)k * 4) = u;
    }
  } else {
    for (int e = (b - 2048) * 256 + t; e < NE; e += 1024 * 256)
      atomicAdd(&deg[dst[e]], 1);
  }
}

// ---------------- CSR build (by destination) ----------------

__global__ void k_blocksum(const int* __restrict__ deg, int* __restrict__ bsum) {
  __shared__ int s[4];
  int i = blockIdx.x * 256 + threadIdx.x;
  int v = (i < NN) ? deg[i] : 0;
  for (int o = 32; o > 0; o >>= 1) v += __shfl_down(v, o);  // wave64 reduce
  if ((threadIdx.x & 63) == 0) s[threadIdx.x >> 6] = v;
  __syncthreads();
  if (threadIdx.x == 0) bsum[blockIdx.x] = s[0] + s[1] + s[2] + s[3];
}

// parallel one-block exclusive scan over NB block sums
__global__ void k_scanpar(int* __restrict__ bsum, int* __restrict__ offs_n) {
  __shared__ int s[256];
  int t = threadIdx.x;
  int v = (t < NB) ? bsum[t] : 0;
  s[t] = v;
  __syncthreads();
  for (int o = 1; o < 256; o <<= 1) {
    int add = (t >= o) ? s[t - o] : 0;
    __syncthreads();
    s[t] += add;
    __syncthreads();
  }
  if (t < NB) bsum[t] = s[t] - v;      // exclusive
  if (t == NB - 1) *offs_n = s[t];     // offs[NN] = NE
}

__global__ void k_offsets(const int* __restrict__ deg, const int* __restrict__ bsum,
                          int* __restrict__ offs) {
  __shared__ int s[256];
  int t = threadIdx.x;
  int i = blockIdx.x * 256 + t;
  int v = (i < NN) ? deg[i] : 0;
  s[t] = v;
  __syncthreads();
  for (int o = 1; o < 256; o <<= 1) {     // Hillis-Steele inclusive scan
    int add = (t >= o) ? s[t - o] : 0;
    __syncthreads();
    s[t] += add;
    __syncthreads();
  }
  if (i < NN) offs[i] = bsum[blockIdx.x] + s[t] - v;  // exclusive
}

// scatter uses deg itself as a countdown cursor (deg dead afterwards)
__global__ void k_scatter(const int* __restrict__ src, const int* __restrict__ dst,
                          const int* __restrict__ offs, int* __restrict__ deg,
                          int* __restrict__ csr) {
  int i = blockIdx.x * blockDim.x + threadIdx.x;
  int stride = gridDim.x * blockDim.x;
  for (int e = i; e < NE; e += stride) {
    int d = dst[e];
    int pos = offs[d] + atomicSub(&deg[d], 1) - 1;
    csr[pos] = src[e];
  }
}

// ---------------- Fused aggregate + MFMA-GEMM(+bias+ReLU) layer ----------------
// Phase A (edge-batched): each wave owns 8 CONTIGUOUS rows; their CSR segment
// is contiguous, so one coalesced 64-wide index load serves ~all 8 rows. Row
// offsets prefetched once (1 load + 9 readlanes). Gathers accumulate into
// per-row register accumulators; cross-row loads pipeline freely.
// Phase B: 3-term hi/lo bf16 MFMA (~fp32 precision).

template <bool OUT_BF16>
__global__ __launch_bounds__(256, 4)
void k_layer(const ushort* __restrict__ feat,      // bf16 features [NN][F]
             const int* __restrict__ offs, const int* __restrict__ csr,
             const ushort* __restrict__ Wpk, int vmul,
             const float* __restrict__ ball, int bstride,
             void* __restrict__ outp) {
  __shared__ ushort sThi[TR][SP];   // 8.7 KB
  __shared__ ushort sTlo[TR][SP];   // 8.7 KB
  const int t = threadIdx.x;
  const int v = blockIdx.y;
  const float* __restrict__ bias = ball + (size_t)v * bstride;

  const int wave = t >> 6, lane = t & 63;
  const int lane15 = lane & 15, lgrp = lane >> 4;
  const int row0 = blockIdx.x * TR;
  const int vcol = v * DF + lane * 2;   // element offset within feature row
  const int lane2 = lane * 2;

  // ---- Phase A ----
  const int base = row0 + wave * 8;     // 8 contiguous rows for this wave

  // Prefetch the 9 row offsets with one coalesced load
  int ow = 0;
  {
    int ri = base + lane;
    if (lane <= 8) {
      if (ri > NN) ri = NN;
      ow = offs[ri];
    }
  }
  int so[9];
#pragma unroll
  for (int k = 0; k < 9; ++k) so[k] = __builtin_amdgcn_readlane(ow, k);

  float ax[8], ay[8];
#pragma unroll
  for (int r = 0; r < 8; ++r) { ax[r] = 0.f; ay[r] = 0.f; }

  const int eb = so[0], ee = so[8];
  for (int chunk = eb; chunk < ee; chunk += 64) {   // wave-uniform
    int ce = chunk + lane; if (ce > ee - 1) ce = ee - 1;
    int idx = csr[ce];                               // one coalesced index load
    int cend = chunk + 64 < ee ? chunk + 64 : ee;
#pragma unroll
    for (int r = 0; r < 8; ++r) {                    // static accumulator index
      int js = so[r] > chunk ? so[r] : chunk;
      int je = so[r + 1] < cend ? so[r + 1] : cend;
      int j  = js - chunk;
      int jn = je - chunk;
      for (; j + 4 <= jn; j += 4) {                  // 4 independent gathers
        int s0 = __builtin_amdgcn_readlane(idx, j);
        int s1 = __builtin_amdgcn_readlane(idx, j + 1);
        int s2 = __builtin_amdgcn_readlane(idx, j + 2);
        int s3 = __builtin_amdgcn_readlane(idx, j + 3);
        unsigned u0 = *(const unsigned*)(feat + (size_t)s0 * F + vcol);
        unsigned u1 = *(const unsigned*)(feat + (size_t)s1 * F + vcol);
        unsigned u2 = *(const unsigned*)(feat + (size_t)s2 * F + vcol);
        unsigned u3 = *(const unsigned*)(feat + (size_t)s3 * F + vcol);
        ax[r] += __uint_as_float(u0 << 16); ay[r] += __uint_as_float(u0 & 0xffff0000u);
        ax[r] += __uint_as_float(u1 << 16); ay[r] += __uint_as_float(u1 & 0xffff0000u);
        ax[r] += __uint_as_float(u2 << 16); ay[r] += __uint_as_float(u2 & 0xffff0000u);
        ax[r] += __uint_as_float(u3 << 16); ay[r] += __uint_as_float(u3 & 0xffff0000u);
      }
      for (; j < jn; ++j) {
        int s0 = __builtin_amdgcn_readlane(idx, j);
        unsigned u0 = *(const unsigned*)(feat + (size_t)s0 * F + vcol);
        ax[r] += __uint_as_float(u0 << 16); ay[r] += __uint_as_float(u0 & 0xffff0000u);
      }
    }
  }

  // hi/lo split of fp32 aggregates -> bf16 arrays in LDS
#pragma unroll
  for (int r = 0; r < 8; ++r) {
    ushort hx = f2bf(ax[r]);
    ushort lx = f2bf(ax[r] - __uint_as_float((unsigned)hx << 16));
    ushort hy = f2bf(ay[r]);
    ushort ly = f2bf(ay[r] - __uint_as_float((unsigned)hy << 16));
    *(unsigned*)&sThi[wave * 8 + r][lane2] = (unsigned)hx | ((unsigned)hy << 16);
    *(unsigned*)&sTlo[wave * 8 + r][lane2] = (unsigned)lx | ((unsigned)ly << 16);
  }
  __syncthreads();

  // ---- Phase B: MFMA GEMM. Wave w -> col-blocks 2w,2w+1; row-blocks 0,1. ----
  const ushort* pkbase = Wpk + (size_t)(v * vmul) * (2 * 4 * 8 * 512);
  const float bv0 = bias[wave * 32 + lane15];
  const float bv1 = bias[wave * 32 + 16 + lane15];
  f32x4 acc00 = {bv0, bv0, bv0, bv0};
  f32x4 acc01 = {bv1, bv1, bv1, bv1};
  f32x4 acc10 = {bv0, bv0, bv0, bv0};
  f32x4 acc11 = {bv1, bv1, bv1, bv1};

#pragma unroll
  for (int kb = 0; kb < 4; ++kb) {
    const int acol = kb * 32 + lgrp * 8;
    bf16x8 ah0 = *(const bf16x8*)&sThi[lane15][acol];
    bf16x8 ah1 = *(const bf16x8*)&sThi[16 + lane15][acol];
    bf16x8 al0 = *(const bf16x8*)&sTlo[lane15][acol];
    bf16x8 al1 = *(const bf16x8*)&sTlo[16 + lane15][acol];
    bf16x8 bh0 = *(const bf16x8*)(pkbase + ((size_t)((0 * 4 + kb) * 8 + wave * 2 + 0)) * 512 + lane * 8);
    bf16x8 bh1 = *(const bf16x8*)(pkbase + ((size_t)((0 * 4 + kb) * 8 + wave * 2 + 1)) * 512 + lane * 8);
    bf16x8 bl0 = *(const bf16x8*)(pkbase + ((size_t)((1 * 4 + kb) * 8 + wave * 2 + 0)) * 512 + lane * 8);
    bf16x8 bl1 = *(const bf16x8*)(pkbase + ((size_t)((1 * 4 + kb) * 8 + wave * 2 + 1)) * 512 + lane * 8);
    acc00 = __builtin_amdgcn_mfma_f32_16x16x32_bf16(ah0, bh0, acc00, 0, 0, 0);
    acc00 = __builtin_amdgcn_mfma_f32_16x16x32_bf16(al0, bh0, acc00, 0, 0, 0);
    acc00 = __builtin_amdgcn_mfma_f32_16x16x32_bf16(ah0, bl0, acc00, 0, 0, 0);
    acc01 = __builtin_amdgcn_mfma_f32_16x16x32_bf16(ah0, bh1, acc01, 0, 0, 0);
    acc01 = __builtin_amdgcn_mfma_f32_16x16x32_bf16(al0, bh1, acc01, 0, 0, 0);
    acc01 = __builtin_amdgcn_mfma_f32_16x16x32_bf16(ah0, bl1, acc01, 0, 0, 0);
    acc10 = __builtin_amdgcn_mfma_f32_16x16x32_bf16(ah1, bh0, acc10, 0, 0, 0);
    acc10 = __builtin_amdgcn_mfma_f32_16x16x32_bf16(al1, bh0, acc10, 0, 0, 0);
    acc10 = __builtin_amdgcn_mfma_f32_16x16x32_bf16(ah1, bl0, acc10, 0, 0, 0);
    acc11 = __builtin_amdgcn_mfma_f32_16x16x32_bf16(ah1, bh1, acc11, 0, 0, 0);
    acc11 = __builtin_amdgcn_mfma_f32_16x16x32_bf16(al1, bh1, acc11, 0, 0, 0);
    acc11 = __builtin_amdgcn_mfma_f32_16x16x32_bf16(ah1, bl1, acc11, 0, 0, 0);
  }

  // ---- Epilogue: relu + store. C/D: col=lane&15, row=(lane>>4)*4+reg ----
  const int colbase = v * DF + wave * 32 + lane15;
#pragma unroll
  for (int rb = 0; rb < 2; ++rb) {
    f32x4 a0 = rb ? acc10 : acc00;
    f32x4 a1 = rb ? acc11 : acc01;
#pragma unroll
    for (int k = 0; k < 4; ++k) {
      int row = row0 + rb * 16 + lgrp * 4 + k;
      if (row < NN) {
        float x0 = a0[k] > 0.f ? a0[k] : 0.f;
        float x1 = a1[k] > 0.f ? a1[k] : 0.f;
        if (OUT_BF16) {
          ushort* ob = (ushort*)outp;
          ob[(size_t)row * F + colbase]      = f2bf(x0);
          ob[(size_t)row * F + colbase + 16] = f2bf(x1);
        } else {
          float* of = (float*)outp;
          of[(size_t)row * F + colbase]      = x0;
          of[(size_t)row * F + colbase + 16] = x1;
        }
      }
    }
  }
}

// ---------------- launch ----------------

static inline size_t align_up(size_t x, size_t a) { return (x + a - 1) & ~(a - 1); }

extern "C" void kernel_launch(void* const* d_in, const int* in_sizes, int n_in,
                              void* d_out, int out_size, void* d_ws, size_t ws_size,
                              hipStream_t stream) {
  const float* h   = (const float*)d_in[0];
  const int*   src = (const int*)d_in[1];
  const int*   dst = (const int*)d_in[2];
  const float* W1  = (const float*)d_in[3];
  const float* b1  = (const float*)d_in[4];
  const float* W2  = (const float*)d_in[5];
  const float* b2  = (const float*)d_in[6];
  float* out = (float*)d_out;

  // Workspace layout
  char* ws = (char*)d_ws;
  size_t o = 0;
  int* deg  = (int*)(ws + o); o = align_up(o + (size_t)NN * 4, 1024);
  int* offs = (int*)(ws + o); o = align_up(o + (size_t)(NN + 1) * 4, 1024);
  int* bsum = (int*)(ws + o); o = align_up(o + 1024, 1024);
  int* csr  = (int*)(ws + o); o = align_up(o + (size_t)NE * 4, 1024);
  ushort* hb   = (ushort*)(ws + o); o = align_up(o + (size_t)NN * F * 2, 1024);  // bf16 h
  ushort* ybuf = (ushort*)(ws + o); o = align_up(o + (size_t)NN * F * 2, 1024);  // bf16 y
  ushort* w1pk = (ushort*)(ws + o); o = align_up(o + (size_t)NV * 2 * 16384 * 2, 1024);
  ushort* w2pk = (ushort*)(ws + o); o = align_up(o + (size_t)1 * 2 * 16384 * 2, 1024);
  (void)ws_size; (void)n_in; (void)in_sizes; (void)out_size;

  // Prep
  k_prep0<<<WB1 + WB2 + NB, 256, 0, stream>>>(W1, W2, w1pk, w2pk, deg);
  k_cvtcnt<<<3072, 256, 0, stream>>>(h, hb, dst, deg);
  k_blocksum<<<NB, 256, 0, stream>>>(deg, bsum);
  k_scanpar<<<1, 256, 0, stream>>>(bsum, offs + NN);
  k_offsets<<<NB, 256, 0, stream>>>(deg, bsum, offs);
  k_scatter<<<1024, 256, 0, stream>>>(src, dst, offs, deg, csr);

  // Two fused layers
  dim3 grid((NN + TR - 1) / TR, NV);
  k_layer<true ><<<grid, 256, 0, stream>>>(hb,   offs, csr, w1pk, 1, b1, DF, ybuf);
  k_layer<false><<<grid, 256, 0, stream>>>(ybuf, offs, csr, w2pk, 0, b2, 0,  out);
}